// Round 1
// baseline (4074.139 us; speedup 1.0000x reference)
//
#include <hip/hip_runtime.h>
#include <stdint.h>
#include <stddef.h>

#define NTS 256

typedef short bf16x8 __attribute__((ext_vector_type(8)));
typedef short bf16x4 __attribute__((ext_vector_type(4)));
typedef float f32x4 __attribute__((ext_vector_type(4)));

__device__ __forceinline__ unsigned short f2bf(float f) {
  union { float f; unsigned u; } c; c.f = f;
  unsigned u = c.u;
  u += 0x7fffu + ((u >> 16) & 1u);   // round-to-nearest-even
  return (unsigned short)(u >> 16);
}

// Repack W1 (64x512) and W2 (512x512) into bf16 K-panels:
// W1P: panel s in 0..1,  layout [s][f(512)][kk(32)]  value = W1[32s+kk][f]
// W2P: panel s in 0..15, layout [s][f2(512)][kk(32)] value = W2[32s+kk][f2]
__global__ __launch_bounds__(256) void prep_weights(const float* __restrict__ W1,
                                                    const float* __restrict__ W2,
                                                    unsigned short* __restrict__ wp) {
  int gid = blockIdx.x * 256 + threadIdx.x;
  if (gid < 32768) {
    int s = gid >> 14, rem = gid & 16383, f = rem >> 5, kk = rem & 31;
    wp[gid] = f2bf(W1[(s * 32 + kk) * 512 + f]);
  } else {
    int e = gid - 32768;
    if (e < 262144) {
      int s = e >> 14, rem = e & 16383, f = rem >> 5, kk = rem & 31;
      wp[32768 + e] = f2bf(W2[(s * 32 + kk) * 512 + f]);
    }
  }
}

// Stage one 32KB panel ([512 rows][32 kk] bf16) into LDS via global_load_lds.
// Each wave moves 4KB: 4 instructions x (64 lanes x 16B).
__device__ __forceinline__ void stage_panel(const unsigned short* __restrict__ src,
                                            char* lds_dst, int wv, int lane) {
#pragma unroll
  for (int i = 0; i < 4; ++i) {
    const unsigned short* g = src + wv * 2048 + i * 512 + lane * 8;
    char* l = lds_dst + wv * 4096 + i * 1024;  // HW adds lane*16
    __builtin_amdgcn_global_load_lds((const __attribute__((address_space(1))) void*)g,
                                     (__attribute__((address_space(3))) void*)l,
                                     16, 0, 0);
  }
}

// LDS map (bytes):
//   [0,      65536)  W-panel double buffer (2 x 32KB)
//   [65536, 131072)  h1: [b(64)][f(512)] bf16, rows 1KB, byte ^= ((b&7)<<4)
//   [131072,139264)  hist: [b(64)][k(64)] bf16, rows 128B, byte ^= ((b&7)<<4)
//   [139264,143360)  pi stage [8 waves][64 b][2] f32
//   [143360,143616)  xs f32[64]
//   [143616,143872)  ys f32[64]
//   [143872,144128)  rs f32[64]
//   [144128,144256)  xnew bf16[64]
//   [144384,146432)  b1 f32[512]
//   [146432,148480)  b2 f32[512]
//   [148480,152576)  W3 f32[512][2]
__global__ __launch_bounds__(512, 2) void po_fused(
    const float* __restrict__ dw, const float* __restrict__ x_init,
    const float* __restrict__ exp_arr, const float* __restrict__ b1,
    const float* __restrict__ b2, const float* __restrict__ W3,
    const float* __restrict__ b3, const unsigned short* __restrict__ wp,
    float* __restrict__ out) {
  extern __shared__ char smem[];
  unsigned short* const h1L = (unsigned short*)(smem + 65536);
  char* const histC = smem + 131072;
  float* const piL = (float*)(smem + 139264);
  float* const xsL = (float*)(smem + 143360);
  float* const ysL = (float*)(smem + 143616);
  float* const rsL = (float*)(smem + 143872);
  unsigned short* const xnbL = (unsigned short*)(smem + 144128);
  float* const b1L = (float*)(smem + 144384);
  float* const b2L = (float*)(smem + 146432);
  float* const w3L = (float*)(smem + 148480);

  const int tid = threadIdx.x;
  const int lane = tid & 63;
  const int wv = tid >> 6;
  const int q = lane >> 4;
  const int j = lane & 15;
  const int wg = blockIdx.x;

  // ---------------- init ----------------
  b1L[tid] = b1[tid];
  b2L[tid] = b2[tid];
  w3L[tid] = W3[tid];
  w3L[tid + 512] = W3[tid + 512];
  {
    // hist[b][k] = bf16(x_init[row][k]), swizzled, one 16B block per thread
    int b = tid >> 3, c = tid & 7;
    const float* src = x_init + ((size_t)wg * 64 + b) * 64 + c * 8;
    bf16x8 v;
#pragma unroll
    for (int e = 0; e < 8; ++e) v[e] = (short)f2bf(src[e]);
    int byte = b * 128 + ((c * 16) ^ ((b & 7) << 4));
    *(bf16x8*)(histC + byte) = v;
  }
  if (tid < 64) {
    const float* row = x_init + ((size_t)wg * 64 + tid) * 64;
    float y0 = 0.f;
    for (int k = 0; k < 63; ++k) y0 += exp_arr[k] * row[1 + k];
    y0 = y0 * 0.04f + (1.f - __expf(-2.52f)) * row[0];  // GEOMETRIC_SUM, lambda=1
    xsL[tid] = row[63];
    ysL[tid] = y0;
    rsL[tid] = 0.f;
  }

  stage_panel(wp, smem, wv, lane);  // prologue: W1 panel 0 -> buf 0

  f32x4 acc[4][4];

  for (int t = 0; t < NTS; ++t) {
#pragma unroll 1
    for (int p = 0; p < 18; ++p) {
      __syncthreads();  // drains vmcnt: panel p staged; prior readers of dest buf done

      {  // stage next panel into the other buffer (weights identical every step)
        int pn = (p == 17) ? 0 : p + 1;
        if (!(t == NTS - 1 && p == 17)) {
          const unsigned short* src =
              wp + (pn < 2 ? pn * 16384 : 32768 + (pn - 2) * 16384);
          stage_panel(src, smem + (((p & 1) ^ 1) * 32768), wv, lane);
        }
      }
      const char* pbuf = smem + (p & 1) * 32768;

      if (p < 2) {
        // ---- Layer 1: h1T = relu(W1T @ histT + b1), kstep = p ----
        if (p == 0) {
#pragma unroll
          for (int mt = 0; mt < 4; ++mt)
#pragma unroll
            for (int nt = 0; nt < 4; ++nt) acc[mt][nt] = (f32x4){0.f, 0.f, 0.f, 0.f};
        }
        bf16x8 bfr[4], afr[4];
#pragma unroll
        for (int nt = 0; nt < 4; ++nt) {
          int b = nt * 16 + j;
          int byte = b * 128 + (((p * 32 + q * 8) * 2) ^ ((b & 7) << 4));
          bfr[nt] = *(const bf16x8*)(histC + byte);
        }
#pragma unroll
        for (int mt = 0; mt < 4; ++mt) {
          int row = wv * 64 + mt * 16 + j;
          afr[mt] = *(const bf16x8*)(pbuf + row * 64 + q * 16);
        }
#pragma unroll
        for (int mt = 0; mt < 4; ++mt)
#pragma unroll
          for (int nt = 0; nt < 4; ++nt)
            acc[mt][nt] = __builtin_amdgcn_mfma_f32_16x16x32_bf16(afr[mt], bfr[nt],
                                                                  acc[mt][nt], 0, 0, 0);
        if (p == 1) {
          // epilogue: relu(+b1) -> bf16 -> h1L[b][f] (4 consecutive f per lane = b64)
#pragma unroll
          for (int mt = 0; mt < 4; ++mt) {
            int f0 = wv * 64 + mt * 16 + q * 4;
#pragma unroll
            for (int nt = 0; nt < 4; ++nt) {
              int b = nt * 16 + j;
              bf16x4 pk;
#pragma unroll
              for (int r = 0; r < 4; ++r) {
                float v = acc[mt][nt][r] + b1L[f0 + r];
                pk[r] = (short)f2bf(fmaxf(v, 0.f));
              }
              int byte = b * 1024 + ((f0 * 2) ^ ((b & 7) << 4));
              *(bf16x4*)((char*)h1L + byte) = pk;
            }
          }
        }
      } else {
        // ---- Layer 2: h2T = W2T @ h1, kstep = p-2 ----
        int ks = p - 2;
        if (p == 2) {
#pragma unroll
          for (int mt = 0; mt < 4; ++mt)
#pragma unroll
            for (int nt = 0; nt < 4; ++nt) acc[mt][nt] = (f32x4){0.f, 0.f, 0.f, 0.f};
        }
        bf16x8 bfr[4], afr[4];
#pragma unroll
        for (int nt = 0; nt < 4; ++nt) {
          int b = nt * 16 + j;
          int byte = b * 1024 + (((ks * 32 + q * 8) * 2) ^ ((b & 7) << 4));
          bfr[nt] = *(const bf16x8*)((const char*)h1L + byte);
        }
#pragma unroll
        for (int mt = 0; mt < 4; ++mt) {
          int row = wv * 64 + mt * 16 + j;
          afr[mt] = *(const bf16x8*)(pbuf + row * 64 + q * 16);
        }
#pragma unroll
        for (int mt = 0; mt < 4; ++mt)
#pragma unroll
          for (int nt = 0; nt < 4; ++nt)
            acc[mt][nt] = __builtin_amdgcn_mfma_f32_16x16x32_bf16(afr[mt], bfr[nt],
                                                                  acc[mt][nt], 0, 0, 0);

        if (p == 17) {
          // ---- Layer 3 folded: pi_partial = sum_f relu(h2+b2)*W3, reduce ----
#pragma unroll
          for (int nt = 0; nt < 4; ++nt) {
            float p0 = 0.f, p1 = 0.f;
#pragma unroll
            for (int mt = 0; mt < 4; ++mt) {
              int f0 = wv * 64 + mt * 16 + q * 4;
#pragma unroll
              for (int r = 0; r < 4; ++r) {
                float v = fmaxf(acc[mt][nt][r] + b2L[f0 + r], 0.f);
                p0 += v * w3L[(f0 + r) * 2];
                p1 += v * w3L[(f0 + r) * 2 + 1];
              }
            }
            p0 += __shfl_xor(p0, 16); p0 += __shfl_xor(p0, 32);
            p1 += __shfl_xor(p1, 16); p1 += __shfl_xor(p1, 32);
            if (q == 0) {
              int b = nt * 16 + j;
              piL[(wv * 64 + b) * 2] = p0;
              piL[(wv * 64 + b) * 2 + 1] = p1;
            }
          }
          __syncthreads();
          // ---- per-row dynamics (wave 0) ----
          if (tid < 64) {
            int b = tid;
            float z0 = b3[0], z1 = b3[1];
#pragma unroll
            for (int w = 0; w < 8; ++w) {
              z0 += piL[(w * 64 + b) * 2];
              z1 += piL[(w * 64 + b) * 2 + 1];
            }
            float pi0 = 2.f / (1.f + __expf(-z0));
            float pi1 = 2.f / (1.f + __expf(-z1));
            float x = xsL[b], y = ysL[b], rw = rsL[b];
            float disc = __expf(-0.004f * (float)t);            // exp(-BETA*DT*t)
            float rv = fmaxf(pi0 * x, 0.f) + 1e-6f;             // relu then +eps
            rw += (__logf(rv) * disc - fmaxf(-x, 0.f) * 100.f) * 0.04f;
            float dwv = dw[((size_t)wg * 64 + b) * NTS + t];
            float dxv = (0.06f * pi1 - pi0 + 0.02f) * x + 0.02f * y;
            float xn = x + dxv * 0.04f + 0.2f * x * pi1 * dwv;
            float yn = y * 0.960789439152323f + xn * 0.04f;     // exp(-DT*LAMBD)
            xsL[b] = xn; ysL[b] = yn; rsL[b] = rw;
            xnbL[b] = f2bf(xn);
          }
          __syncthreads();
          // ---- hist shift: new[k]=old[k+1], new[63]=x_new; reg-side, no hazard ----
          {
            int b = tid >> 3, c = tid & 7;
            int byte = b * 128 + ((c * 16) ^ ((b & 7) << 4));
            bf16x8 blk = *(bf16x8*)(histC + byte);
            int e0 = (int)(unsigned short)blk[0];
            int nb = __shfl_down(e0, 1);  // same 8-thread row group, same wave
            bf16x8 nw;
#pragma unroll
            for (int e = 0; e < 7; ++e) nw[e] = blk[e + 1];
            nw[7] = (c == 7) ? (short)xnbL[b] : (short)(unsigned short)nb;
            *(bf16x8*)(histC + byte) = nw;
          }
        }
      }
    }
  }

  __syncthreads();
  if (tid < 64) {
    float x = xsL[tid], y = ysL[tid], rw = rsL[tid];
    rw += __logf(fmaxf(x + 0.5f * y, 0.f) + 1e-6f) * 10.f * __expf(-1.024f);
    rw -= fmaxf(-x, 0.f) * 100.f;
    out[(size_t)wg * 64 + tid] = -rw;
  }
}

extern "C" void kernel_launch(void* const* d_in, const int* in_sizes, int n_in,
                              void* d_out, int out_size, void* d_ws, size_t ws_size,
                              hipStream_t stream) {
  const float* dw      = (const float*)d_in[0];
  const float* x_init  = (const float*)d_in[1];
  const float* exp_arr = (const float*)d_in[2];
  const float* W1      = (const float*)d_in[3];
  const float* b1      = (const float*)d_in[4];
  const float* W2      = (const float*)d_in[5];
  const float* b2      = (const float*)d_in[6];
  const float* W3      = (const float*)d_in[7];
  const float* b3      = (const float*)d_in[8];
  unsigned short* wp = (unsigned short*)d_ws;  // needs 576KB
  float* out = (float*)d_out;

  (void)hipFuncSetAttribute((const void*)po_fused,
                            hipFuncAttributeMaxDynamicSharedMemorySize, 160 * 1024);

  prep_weights<<<1152, 256, 0, stream>>>(W1, W2, wp);
  po_fused<<<256, 512, 152576, stream>>>(dw, x_init, exp_arr, b1, b2, W3, b3, wp, out);
}